// Round 12
// baseline (833.067 us; speedup 1.0000x reference)
//
#include <hip/hip_runtime.h>
#include <hip/hip_fp16.h>
#include <cstdint>

// Problem constants (match reference)
constexpr int N_NODES = 100000;
constexpr int E_EDGES = 1600000;
constexpr float NEG_SLOPE = 0.2f;
constexpr float INV_TEMP = 1.0f / 0.7f;

// Partition/bucket geometry
constexpr int NPART = 8;
constexpr int PART_N = N_NODES / NPART;          // 12500
constexpr int BKT_NODES = 64;                    // nodes per bucket
constexpr int NBKT_PART = (PART_N + BKT_NODES - 1) / BKT_NODES;  // 196
constexpr int NBKT = NPART * NBKT_PART;          // 1568
constexpr int REG_B = 1792;                      // recs per bucket (mean 1024, +17 sigma)
constexpr int THALF = 8192;                      // edges per k_split tile
constexpr int NTH = (E_EDGES + THALF - 1) / THALF;  // 196
constexpr int CAPK = 1344;                       // kept per (part,tile): mean 1024, +10.6 sigma

constexpr int MLP_B = 2;
constexpr int MLP_T = E_EDGES / MLP_B;           // 800000

__device__ __forceinline__ __half2 bits_to_h2(int bits) {
    return *reinterpret_cast<__half2*>(&bits);
}

// packed relu (no __hmax2 in ROCm 7.2 headers; __hgt2 gives packed 1/0 mask)
__device__ __forceinline__ __half2 h2_relu(__half2 a) {
    const __half2 z = __floats2half2_rn(0.f, 0.f);
    return __hmul2(a, __hgt2(a, z));
}

// ---------------------------------------------------------------------------
// K1: per-node transform. xp2[n][c] = half2(head0_c, head1_c); a_src/a_dst
//     dots [N,2] fp32. Fused: zero gcur[1568], pack w2 -> w2h[16].
// ---------------------------------------------------------------------------
__global__ void k_node(const float* __restrict__ x, const float* __restrict__ W,
                       const float* __restrict__ att_src, const float* __restrict__ att_dst,
                       __half2* __restrict__ xp2, float* __restrict__ a_src,
                       float* __restrict__ a_dst, int* __restrict__ gcur,
                       const float* __restrict__ w2, __half2* __restrict__ w2h) {
    int n = blockIdx.x * blockDim.x + threadIdx.x;
    if (blockIdx.x == 0 && threadIdx.x < 16)
        w2h[threadIdx.x] = __floats2half2_rn(w2[2 * threadIdx.x], w2[2 * threadIdx.x + 1]);
    if (n < NBKT) gcur[n] = 0;
    if (n >= N_NODES) return;
    float xi[16];
    const float4* xv = (const float4*)(x + (size_t)n * 16);
    ((float4*)xi)[0] = xv[0];
    ((float4*)xi)[1] = xv[1];
    ((float4*)xi)[2] = xv[2];
    ((float4*)xi)[3] = xv[3];
    float as0 = 0.f, as1 = 0.f, ad0 = 0.f, ad1 = 0.f;
    __half2 hbuf[32];
#pragma unroll
    for (int c = 0; c < 32; c++) {
        float acc0 = 0.f, acc1 = 0.f;
#pragma unroll
        for (int k = 0; k < 16; k++) {
            acc0 += xi[k] * W[k * 64 + c];
            acc1 += xi[k] * W[k * 64 + 32 + c];
        }
        hbuf[c] = __floats2half2_rn(acc0, acc1);
        as0 += acc0 * att_src[c];
        as1 += acc1 * att_src[32 + c];
        ad0 += acc0 * att_dst[c];
        ad1 += acc1 * att_dst[32 + c];
    }
    float4* dst4 = (float4*)(xp2 + (size_t)n * 32);
#pragma unroll
    for (int q = 0; q < 8; q++) dst4[q] = ((float4*)hbuf)[q];
    ((float2*)a_src)[n] = make_float2(as0, as1);
    ((float2*)a_dst)[n] = make_float2(ad0, ad1);
}

// ---------------------------------------------------------------------------
// K2 (k_split): one block per (partition, 8192-edge tile). Two-pass LDS
//     counting sort; all global record writes are coalesced segments.
//     Record: {s | dloc<<17, half2(w0,w1)}  (s<2^17, dloc<2^14)
// ---------------------------------------------------------------------------
__global__ void __launch_bounds__(256) k_split(
        const int* __restrict__ src, const int* __restrict__ dst,
        const float* __restrict__ a_src, const float* __restrict__ a_dst,
        int* __restrict__ gcur, int2* __restrict__ recs_g) {
    __shared__ int2 lrec[CAPK];        // 10.8 KB
    __shared__ int hist[256];          // 196 used, padded for scan
    __shared__ int sc[256];
    __shared__ int cnt2[NBKT_PART];
    __shared__ int gbase[NBKT_PART];

    int part = blockIdx.x & 7;
    int th = blockIdx.x >> 3;          // 0..195
    int tid = threadIdx.x;
    int lo = part * PART_N, hi = lo + PART_N;
    int ebase = th * THALF;

    hist[tid] = 0;
    if (tid < NBKT_PART) cnt2[tid] = 0;
    __syncthreads();

    // pass A: histogram (dst row only)
#pragma unroll
    for (int it = 0; it < THALF / (256 * 4); it++) {
        int e4 = ebase + (it * 256 + tid) * 4;
        if (e4 + 3 < E_EDGES) {
            int4 d4 = *(const int4*)(dst + e4);
            if (d4.x >= lo && d4.x < hi) atomicAdd(&hist[(d4.x - lo) >> 6], 1);
            if (d4.y >= lo && d4.y < hi) atomicAdd(&hist[(d4.y - lo) >> 6], 1);
            if (d4.z >= lo && d4.z < hi) atomicAdd(&hist[(d4.z - lo) >> 6], 1);
            if (d4.w >= lo && d4.w < hi) atomicAdd(&hist[(d4.w - lo) >> 6], 1);
        } else if (e4 < E_EDGES) {
            int nv = E_EDGES - e4;
            for (int k = 0; k < nv; k++) {
                int d = dst[e4 + k];
                if (d >= lo && d < hi) atomicAdd(&hist[(d - lo) >> 6], 1);
            }
        }
    }
    __syncthreads();

    // inclusive scan hist -> sc (256-wide)
    sc[tid] = hist[tid];
    __syncthreads();
    for (int off = 1; off < 256; off <<= 1) {
        int v = (tid >= off) ? sc[tid - off] : 0;
        __syncthreads();
        sc[tid] += v;
        __syncthreads();
    }

    // reserve global space (one atomic per bucket per block)
    if (tid < NBKT_PART)
        gbase[tid] = atomicAdd(&gcur[part * NBKT_PART + tid], hist[tid]);
    __syncthreads();

    // pass B: compute weights, write to bucket-grouped LDS slots
#pragma unroll
    for (int it = 0; it < THALF / (256 * 4); it++) {
        int e4 = ebase + (it * 256 + tid) * 4;
        int dd[4], ss[4], nv = 0;
        if (e4 + 3 < E_EDGES) {
            int4 d4 = *(const int4*)(dst + e4);
            int4 s4 = *(const int4*)(src + e4);
            dd[0] = d4.x; dd[1] = d4.y; dd[2] = d4.z; dd[3] = d4.w;
            ss[0] = s4.x; ss[1] = s4.y; ss[2] = s4.z; ss[3] = s4.w;
            nv = 4;
        } else if (e4 < E_EDGES) {
            nv = E_EDGES - e4;
            for (int k = 0; k < nv; k++) { dd[k] = dst[e4 + k]; ss[k] = src[e4 + k]; }
        }
        for (int k = 0; k < nv; k++) {
            int d = dd[k];
            if (d >= lo && d < hi) {
                int s = ss[k];
                float2 As = ((const float2*)a_src)[s];
                float2 Ad = ((const float2*)a_dst)[d];
                float e0 = As.x + Ad.x; e0 = (e0 > 0.f) ? e0 : NEG_SLOPE * e0;
                float e1 = As.y + Ad.y; e1 = (e1 > 0.f) ? e1 : NEG_SLOPE * e1;
                __half2 hw = __floats2half2_rn(__expf(e0), __expf(e1));
                int wb = *reinterpret_cast<int*>(&hw);
                int dloc = d - lo;
                int b = dloc >> 6;
                int posl = ((b > 0) ? sc[b - 1] : 0) + atomicAdd(&cnt2[b], 1);
                if (posl < CAPK) lrec[posl] = make_int2(s | (dloc << 17), wb);
            }
        }
    }
    __syncthreads();

    // pass C: coalesced segment write-out
    int kc = sc[NBKT_PART - 1]; if (kc > CAPK) kc = CAPK;
    for (int i = tid; i < kc; i += 256) {
        int2 rc = lrec[i];
        int b = rc.x >> 23;                       // dloc>>6
        int excl = (b > 0) ? sc[b - 1] : 0;
        int gpos = gbase[b] + (i - excl);
        if (gpos < REG_B)
            recs_g[(size_t)(part * NBKT_PART + b) * REG_B + gpos] = rc;
    }
}

// ---------------------------------------------------------------------------
// K3 (k_aggsum): one block per 64-node bucket. NO SORT: each half-wave
//     streams an equal chunk of the bucket's (unsorted) records and
//     accumulates via LDS float atomics:
//       sacc0[nl][ch] += w0*x0   sacc1[nl][ch] += w1*x1   (bank = ch: no
//     conflicts within a 32-lane group; 2 lanes/bank across wave = free).
//     Accumulation is fire-and-forget -> no dependent chain, no divergence,
//     perfect half-wave balance, 3 LDS ops/edge (vs ~5 + 5 barriers before).
//     Epilogue: + self-loop (fp32), softmax mean, fused u/v factorization.
// ---------------------------------------------------------------------------
__global__ void __launch_bounds__(256) k_aggsum(
        const int2* __restrict__ recs_g, const int* __restrict__ gcur,
        const float* __restrict__ a_src, const float* __restrict__ a_dst,
        const __half2* __restrict__ xp2, const float* __restrict__ bias,
        const float* __restrict__ w1, const float* __restrict__ b1,
        __half* __restrict__ u, __half* __restrict__ v) {
    __shared__ float sacc0[BKT_NODES * 32];   // 8 KB
    __shared__ float sacc1[BKT_NODES * 32];   // 8 KB
    __shared__ float sden[2 * BKT_NODES];     // 512 B

    int gb = blockIdx.x;
    int part = gb / NBKT_PART;
    int lb = gb - part * NBKT_PART;
    int node0 = part * PART_N + lb * BKT_NODES;
    int nnodes = PART_N - lb * BKT_NODES;
    if (nnodes > BKT_NODES) nnodes = BKT_NODES;
    int tid = threadIdx.x;

    for (int i = tid; i < BKT_NODES * 32; i += 256) { sacc0[i] = 0.f; sacc1[i] = 0.f; }
    if (tid < 2 * BKT_NODES) sden[tid] = 0.f;
    __syncthreads();

    int cnt = gcur[gb]; if (cnt > REG_B) cnt = REG_B;
    const int2* breg = recs_g + (size_t)gb * REG_B;
    int hwl = tid >> 5, ch = tid & 31;

    int chunk = (cnt + 7) >> 3;
    int start = hwl * chunk;
    int end = start + chunk; if (end > cnt) end = cnt;

    constexpr int U = 8;
    for (int j = start; j < end; j += U) {
        int2 rc[U];
#pragma unroll
        for (int k = 0; k < U; k++) {
            int idx = j + k;
            idx = (idx < end) ? idx : (end - 1);
            rc[k] = breg[idx];                 // broadcast L2-hot line read
        }
        __half2 xv[U];
#pragma unroll
        for (int k = 0; k < U; k++)
            xv[k] = xp2[(rc[k].x & 0x1FFFF) * 32 + ch];
#pragma unroll
        for (int k = 0; k < U; k++) {
            float2 wf = __half22float2(bits_to_h2(rc[k].y));
            if (j + k >= end) { wf.x = 0.f; wf.y = 0.f; }   // mask tail dups
            float2 xf = __half22float2(xv[k]);
            int nl = (rc[k].x >> 17) & 63;
            atomicAdd(&sacc0[nl * 32 + ch], wf.x * xf.x);
            atomicAdd(&sacc1[nl * 32 + ch], wf.y * xf.y);
            if (ch < 2) atomicAdd(&sden[ch * BKT_NODES + nl], ch ? wf.y : wf.x);
        }
    }
    __syncthreads();

    // epilogue: self-loop + softmax head-mean + fused u/v MLP factorization
    for (int nl = hwl; nl < nnodes; nl += 8) {
        int d = node0 + nl;
        float2 Ad  = ((const float2*)a_dst)[d];
        float2 As0 = ((const float2*)a_src)[d];
        float e0 = As0.x + Ad.x; e0 = (e0 > 0.f) ? e0 : NEG_SLOPE * e0;
        float e1 = As0.y + Ad.y; e1 = (e1 > 0.f) ? e1 : NEG_SLOPE * e1;
        float w00 = __expf(e0), w01 = __expf(e1);
        float2 xself = __half22float2(xp2[d * 32 + ch]);

        float num0 = sacc0[nl * 32 + ch] + w00 * xself.x;
        float num1 = sacc1[nl * 32 + ch] + w01 * xself.y;
        float den0 = sden[nl] + w00;
        float den1 = sden[BKT_NODES + nl] + w01;

        float h = 0.5f * (num0 / (den0 + 1e-16f) + num1 / (den1 + 1e-16f)) + bias[ch];

        float uu = b1[ch], vv = 0.f;
#pragma unroll
        for (int c = 0; c < 32; c++) {
            float hc = __shfl(h, c, 32);
            uu += hc * w1[c * 32 + ch];
            vv += hc * w1[(32 + c) * 32 + ch];
        }
        u[d * 32 + ch] = __float2half(uu);
        v[d * 32 + ch] = __float2half(vv);
    }
}

// ---------------------------------------------------------------------------
// K4: per-edge logits in original edge order (coalesced out writes),
//     2 edges/thread. u/v fp16 rows gathered; packed-half2 dot, fp32 combine.
// ---------------------------------------------------------------------------
__global__ void k_mlp(const int* __restrict__ src, const int* __restrict__ dst,
                      const __half2* __restrict__ u2, const __half2* __restrict__ v2,
                      const __half2* __restrict__ w2h, const float* __restrict__ b2,
                      float* __restrict__ out) {
    int t = blockIdx.x * blockDim.x + threadIdx.x;
    if (t >= MLP_T) return;
    __half2 wl[16];
#pragma unroll
    for (int q = 0; q < 4; q++) ((float4*)wl)[q] = ((const float4*)w2h)[q];
    int s[MLP_B], d[MLP_B];
#pragma unroll
    for (int k = 0; k < MLP_B; k++) {
        s[k] = src[t + k * MLP_T];
        d[k] = dst[t + k * MLP_T];
    }
    float4 ua[MLP_B][4], va[MLP_B][4];
#pragma unroll
    for (int k = 0; k < MLP_B; k++) {
        const float4* up4 = (const float4*)(u2 + s[k] * 16);
        const float4* vp4 = (const float4*)(v2 + d[k] * 16);
#pragma unroll
        for (int q = 0; q < 4; q++) { ua[k][q] = up4[q]; va[k][q] = vp4[q]; }
    }
#pragma unroll
    for (int k = 0; k < MLP_B; k++) {
        const __half2* uh = (const __half2*)ua[k];
        const __half2* vh = (const __half2*)va[k];
        const __half2 z2 = __floats2half2_rn(0.f, 0.f);
        __half2 acc0 = z2, acc1 = z2, acc2 = z2, acc3 = z2;
#pragma unroll
        for (int q = 0; q < 16; q += 4) {
            acc0 = __hfma2(h2_relu(__hadd2(uh[q + 0], vh[q + 0])), wl[q + 0], acc0);
            acc1 = __hfma2(h2_relu(__hadd2(uh[q + 1], vh[q + 1])), wl[q + 1], acc1);
            acc2 = __hfma2(h2_relu(__hadd2(uh[q + 2], vh[q + 2])), wl[q + 2], acc2);
            acc3 = __hfma2(h2_relu(__hadd2(uh[q + 3], vh[q + 3])), wl[q + 3], acc3);
        }
        float2 f0 = __half22float2(acc0);
        float2 f1 = __half22float2(acc1);
        float2 f2 = __half22float2(acc2);
        float2 f3 = __half22float2(acc3);
        float acc = b2[0] + (f0.x + f0.y) + (f1.x + f1.y) + (f2.x + f2.y) + (f3.x + f3.y);
        out[t + k * MLP_T] = acc * INV_TEMP;
    }
}

// ---------------------------------------------------------------------------
extern "C" void kernel_launch(void* const* d_in, const int* in_sizes, int n_in,
                              void* d_out, int out_size, void* d_ws, size_t ws_size,
                              hipStream_t stream) {
    const float* x       = (const float*)d_in[0];
    const int*   eidx    = (const int*)d_in[1];          // [2,E] int32
    const float* W       = (const float*)d_in[2];
    const float* att_src = (const float*)d_in[3];
    const float* att_dst = (const float*)d_in[4];
    const float* bias    = (const float*)d_in[5];
    const float* w1      = (const float*)d_in[6];
    const float* b1      = (const float*)d_in[7];
    const float* w2      = (const float*)d_in[8];
    const float* b2      = (const float*)d_in[9];
    float* out = (float*)d_out;

    const int* src = eidx;             // row 0
    const int* dst = eidx + E_EDGES;   // row 1

    // Workspace layout (~50 MB; 16B alignment holds at each boundary).
    int* gcur     = (int*)d_ws;                      // 1568 (zeroed in k_node)
    __half2* w2h  = (__half2*)(gcur + NBKT);         // 16 half2 (64 B)
    int2* recs_g  = (int2*)(w2h + 16);               // NBKT*REG_B recs (22.5 MB)
    float* a_src  = (float*)(recs_g + (size_t)NBKT * REG_B);  // 2N
    float* a_dst  = a_src + 2 * N_NODES;             // 2N
    __half2* xp2  = (__half2*)(a_dst + 2 * N_NODES); // 32N half2 (12.8 MB)
    __half* u     = (__half*)(xp2 + 32 * (size_t)N_NODES);  // 32N halves (6.4 MB)
    __half* v     = u + 32 * (size_t)N_NODES;               // 32N halves (6.4 MB)

    constexpr int BS = 256;

    // K1: node transform (+ gcur zero + w2 pack, fused)
    k_node<<<(N_NODES + BS - 1) / BS, BS, 0, stream>>>(x, W, att_src, att_dst,
                                                      xp2, a_src, a_dst, gcur, w2, w2h);

    // K2: per-(partition,tile) two-pass LDS counting sort -> bucketed records
    k_split<<<NPART * NTH, BS, 0, stream>>>(src, dst, a_src, a_dst, gcur, recs_g);

    // K3: per-bucket streaming aggregation via LDS float atomics (no sort)
    k_aggsum<<<NBKT, BS, 0, stream>>>(recs_g, gcur, a_src, a_dst, xp2,
                                      bias, w1, b1, u, v);

    // K4: per-edge logits (edge order, 2 edges/thread)
    k_mlp<<<(MLP_T + BS - 1) / BS, BS, 0, stream>>>(src, dst, (const __half2*)u,
                                                   (const __half2*)v, w2h, b2, out);
}

// Round 13
// 832.295 us; speedup vs baseline: 1.0009x; 1.0009x over previous
//
#include <hip/hip_runtime.h>
#include <hip/hip_fp16.h>
#include <cstdint>

// Problem constants (match reference)
constexpr int N_NODES = 100000;
constexpr int E_EDGES = 1600000;
constexpr float NEG_SLOPE = 0.2f;
constexpr float INV_TEMP = 1.0f / 0.7f;

// Partition/bucket geometry
constexpr int NPART = 8;
constexpr int PART_N = N_NODES / NPART;          // 12500
constexpr int BKT_NODES = 64;                    // nodes per bucket
constexpr int NBKT_PART = (PART_N + BKT_NODES - 1) / BKT_NODES;  // 196
constexpr int NBKT = NPART * NBKT_PART;          // 1568
constexpr int REG_B = 1792;                      // recs per bucket (mean 1024, +17 sigma)
constexpr int THALF = 8192;                      // edges per k_split tile
constexpr int NTH = (E_EDGES + THALF - 1) / THALF;  // 196
constexpr int CAPK = 1344;                       // kept per (part,tile): mean 1024, +10.6 sigma

constexpr int MLP_B = 2;
constexpr int MLP_T = E_EDGES / MLP_B;           // 800000

__device__ __forceinline__ __half2 bits_to_h2(int bits) {
    return *reinterpret_cast<__half2*>(&bits);
}

// packed relu (no __hmax2 in ROCm 7.2 headers; __hgt2 gives packed 1/0 mask)
__device__ __forceinline__ __half2 h2_relu(__half2 a) {
    const __half2 z = __floats2half2_rn(0.f, 0.f);
    return __hmul2(a, __hgt2(a, z));
}

// ---------------------------------------------------------------------------
// K1: per-node transform. xp2[n][c] = half2(head0_c, head1_c); a_src/a_dst
//     dots [N,2] fp32. Fused: zero gcur[1568], pack w2 -> w2h[16].
// ---------------------------------------------------------------------------
__global__ void k_node(const float* __restrict__ x, const float* __restrict__ W,
                       const float* __restrict__ att_src, const float* __restrict__ att_dst,
                       __half2* __restrict__ xp2, float* __restrict__ a_src,
                       float* __restrict__ a_dst, int* __restrict__ gcur,
                       const float* __restrict__ w2, __half2* __restrict__ w2h) {
    int n = blockIdx.x * blockDim.x + threadIdx.x;
    if (blockIdx.x == 0 && threadIdx.x < 16)
        w2h[threadIdx.x] = __floats2half2_rn(w2[2 * threadIdx.x], w2[2 * threadIdx.x + 1]);
    if (n < NBKT) gcur[n] = 0;
    if (n >= N_NODES) return;
    float xi[16];
    const float4* xv = (const float4*)(x + (size_t)n * 16);
    ((float4*)xi)[0] = xv[0];
    ((float4*)xi)[1] = xv[1];
    ((float4*)xi)[2] = xv[2];
    ((float4*)xi)[3] = xv[3];
    float as0 = 0.f, as1 = 0.f, ad0 = 0.f, ad1 = 0.f;
    __half2 hbuf[32];
#pragma unroll
    for (int c = 0; c < 32; c++) {
        float acc0 = 0.f, acc1 = 0.f;
#pragma unroll
        for (int k = 0; k < 16; k++) {
            acc0 += xi[k] * W[k * 64 + c];
            acc1 += xi[k] * W[k * 64 + 32 + c];
        }
        hbuf[c] = __floats2half2_rn(acc0, acc1);
        as0 += acc0 * att_src[c];
        as1 += acc1 * att_src[32 + c];
        ad0 += acc0 * att_dst[c];
        ad1 += acc1 * att_dst[32 + c];
    }
    float4* dst4 = (float4*)(xp2 + (size_t)n * 32);
#pragma unroll
    for (int q = 0; q < 8; q++) dst4[q] = ((float4*)hbuf)[q];
    ((float2*)a_src)[n] = make_float2(as0, as1);
    ((float2*)a_dst)[n] = make_float2(ad0, ad1);
}

// ---------------------------------------------------------------------------
// K2 (k_split): one block per (partition, 8192-edge tile). Two-pass LDS
//     counting sort; all global record writes are coalesced segments.
//     Record: {s | dloc<<17, half2(w0,w1)}  (s<2^17, dloc<2^14)
// ---------------------------------------------------------------------------
__global__ void __launch_bounds__(256) k_split(
        const int* __restrict__ src, const int* __restrict__ dst,
        const float* __restrict__ a_src, const float* __restrict__ a_dst,
        int* __restrict__ gcur, int2* __restrict__ recs_g) {
    __shared__ int2 lrec[CAPK];        // 10.8 KB
    __shared__ int hist[256];          // 196 used, padded for scan
    __shared__ int sc[256];
    __shared__ int cnt2[NBKT_PART];
    __shared__ int gbase[NBKT_PART];

    int part = blockIdx.x & 7;
    int th = blockIdx.x >> 3;          // 0..195
    int tid = threadIdx.x;
    int lo = part * PART_N, hi = lo + PART_N;
    int ebase = th * THALF;

    hist[tid] = 0;
    if (tid < NBKT_PART) cnt2[tid] = 0;
    __syncthreads();

    // pass A: histogram (dst row only)
#pragma unroll
    for (int it = 0; it < THALF / (256 * 4); it++) {
        int e4 = ebase + (it * 256 + tid) * 4;
        if (e4 + 3 < E_EDGES) {
            int4 d4 = *(const int4*)(dst + e4);
            if (d4.x >= lo && d4.x < hi) atomicAdd(&hist[(d4.x - lo) >> 6], 1);
            if (d4.y >= lo && d4.y < hi) atomicAdd(&hist[(d4.y - lo) >> 6], 1);
            if (d4.z >= lo && d4.z < hi) atomicAdd(&hist[(d4.z - lo) >> 6], 1);
            if (d4.w >= lo && d4.w < hi) atomicAdd(&hist[(d4.w - lo) >> 6], 1);
        } else if (e4 < E_EDGES) {
            int nv = E_EDGES - e4;
            for (int k = 0; k < nv; k++) {
                int d = dst[e4 + k];
                if (d >= lo && d < hi) atomicAdd(&hist[(d - lo) >> 6], 1);
            }
        }
    }
    __syncthreads();

    // inclusive scan hist -> sc (256-wide)
    sc[tid] = hist[tid];
    __syncthreads();
    for (int off = 1; off < 256; off <<= 1) {
        int v = (tid >= off) ? sc[tid - off] : 0;
        __syncthreads();
        sc[tid] += v;
        __syncthreads();
    }

    // reserve global space (one atomic per bucket per block)
    if (tid < NBKT_PART)
        gbase[tid] = atomicAdd(&gcur[part * NBKT_PART + tid], hist[tid]);
    __syncthreads();

    // pass B: compute weights, write to bucket-grouped LDS slots
#pragma unroll
    for (int it = 0; it < THALF / (256 * 4); it++) {
        int e4 = ebase + (it * 256 + tid) * 4;
        int dd[4], ss[4], nv = 0;
        if (e4 + 3 < E_EDGES) {
            int4 d4 = *(const int4*)(dst + e4);
            int4 s4 = *(const int4*)(src + e4);
            dd[0] = d4.x; dd[1] = d4.y; dd[2] = d4.z; dd[3] = d4.w;
            ss[0] = s4.x; ss[1] = s4.y; ss[2] = s4.z; ss[3] = s4.w;
            nv = 4;
        } else if (e4 < E_EDGES) {
            nv = E_EDGES - e4;
            for (int k = 0; k < nv; k++) { dd[k] = dst[e4 + k]; ss[k] = src[e4 + k]; }
        }
        for (int k = 0; k < nv; k++) {
            int d = dd[k];
            if (d >= lo && d < hi) {
                int s = ss[k];
                float2 As = ((const float2*)a_src)[s];
                float2 Ad = ((const float2*)a_dst)[d];
                float e0 = As.x + Ad.x; e0 = (e0 > 0.f) ? e0 : NEG_SLOPE * e0;
                float e1 = As.y + Ad.y; e1 = (e1 > 0.f) ? e1 : NEG_SLOPE * e1;
                __half2 hw = __floats2half2_rn(__expf(e0), __expf(e1));
                int wb = *reinterpret_cast<int*>(&hw);
                int dloc = d - lo;
                int b = dloc >> 6;
                int posl = ((b > 0) ? sc[b - 1] : 0) + atomicAdd(&cnt2[b], 1);
                if (posl < CAPK) lrec[posl] = make_int2(s | (dloc << 17), wb);
            }
        }
    }
    __syncthreads();

    // pass C: coalesced segment write-out
    int kc = sc[NBKT_PART - 1]; if (kc > CAPK) kc = CAPK;
    for (int i = tid; i < kc; i += 256) {
        int2 rc = lrec[i];
        int b = rc.x >> 23;                       // dloc>>6
        int excl = (b > 0) ? sc[b - 1] : 0;
        int gpos = gbase[b] + (i - excl);
        if (gpos < REG_B)
            recs_g[(size_t)(part * NBKT_PART + b) * REG_B + gpos] = rc;
    }
}

// ---------------------------------------------------------------------------
// K3 (k_aggsum): one block per 64-node bucket. NO SORT: each half-wave
//     streams an equal chunk of unsorted bucket records and accumulates via
//     NATIVE LDS float atomics (unsafeAtomicAdd -> ds_add_f32; plain
//     atomicAdd(float*) lowers to a CAS retry loop = R12's 10x regression).
//     Bank = ch -> conflict-free in a 32-lane group.
//     Epilogue: + self-loop (fp32), softmax mean, fused u/v factorization.
// ---------------------------------------------------------------------------
__global__ void __launch_bounds__(256) k_aggsum(
        const int2* __restrict__ recs_g, const int* __restrict__ gcur,
        const float* __restrict__ a_src, const float* __restrict__ a_dst,
        const __half2* __restrict__ xp2, const float* __restrict__ bias,
        const float* __restrict__ w1, const float* __restrict__ b1,
        __half* __restrict__ u, __half* __restrict__ v) {
    __shared__ float sacc0[BKT_NODES * 32];   // 8 KB
    __shared__ float sacc1[BKT_NODES * 32];   // 8 KB
    __shared__ float sden[2 * BKT_NODES];     // 512 B

    int gb = blockIdx.x;
    int part = gb / NBKT_PART;
    int lb = gb - part * NBKT_PART;
    int node0 = part * PART_N + lb * BKT_NODES;
    int nnodes = PART_N - lb * BKT_NODES;
    if (nnodes > BKT_NODES) nnodes = BKT_NODES;
    int tid = threadIdx.x;

    for (int i = tid; i < BKT_NODES * 32; i += 256) { sacc0[i] = 0.f; sacc1[i] = 0.f; }
    if (tid < 2 * BKT_NODES) sden[tid] = 0.f;
    __syncthreads();

    int cnt = gcur[gb]; if (cnt > REG_B) cnt = REG_B;
    const int2* breg = recs_g + (size_t)gb * REG_B;
    int hwl = tid >> 5, ch = tid & 31;

    int chunk = (cnt + 7) >> 3;
    int start = hwl * chunk;
    int end = start + chunk; if (end > cnt) end = cnt;

    constexpr int U = 8;
    for (int j = start; j < end; j += U) {
        int2 rc[U];
#pragma unroll
        for (int k = 0; k < U; k++) {
            int idx = j + k;
            idx = (idx < end) ? idx : (end - 1);
            rc[k] = breg[idx];                 // broadcast L2-hot line read
        }
        __half2 xv[U];
#pragma unroll
        for (int k = 0; k < U; k++)
            xv[k] = xp2[(rc[k].x & 0x1FFFF) * 32 + ch];
#pragma unroll
        for (int k = 0; k < U; k++) {
            float2 wf = __half22float2(bits_to_h2(rc[k].y));
            if (j + k >= end) { wf.x = 0.f; wf.y = 0.f; }   // mask tail dups
            float2 xf = __half22float2(xv[k]);
            int nl = (rc[k].x >> 17) & 63;
            unsafeAtomicAdd(&sacc0[nl * 32 + ch], wf.x * xf.x);
            unsafeAtomicAdd(&sacc1[nl * 32 + ch], wf.y * xf.y);
            if (ch < 2) unsafeAtomicAdd(&sden[ch * BKT_NODES + nl], ch ? wf.y : wf.x);
        }
    }
    __syncthreads();

    // epilogue: self-loop + softmax head-mean + fused u/v MLP factorization
    for (int nl = hwl; nl < nnodes; nl += 8) {
        int d = node0 + nl;
        float2 Ad  = ((const float2*)a_dst)[d];
        float2 As0 = ((const float2*)a_src)[d];
        float e0 = As0.x + Ad.x; e0 = (e0 > 0.f) ? e0 : NEG_SLOPE * e0;
        float e1 = As0.y + Ad.y; e1 = (e1 > 0.f) ? e1 : NEG_SLOPE * e1;
        float w00 = __expf(e0), w01 = __expf(e1);
        float2 xself = __half22float2(xp2[d * 32 + ch]);

        float num0 = sacc0[nl * 32 + ch] + w00 * xself.x;
        float num1 = sacc1[nl * 32 + ch] + w01 * xself.y;
        float den0 = sden[nl] + w00;
        float den1 = sden[BKT_NODES + nl] + w01;

        float h = 0.5f * (num0 / (den0 + 1e-16f) + num1 / (den1 + 1e-16f)) + bias[ch];

        float uu = b1[ch], vv = 0.f;
#pragma unroll
        for (int c = 0; c < 32; c++) {
            float hc = __shfl(h, c, 32);
            uu += hc * w1[c * 32 + ch];
            vv += hc * w1[(32 + c) * 32 + ch];
        }
        u[d * 32 + ch] = __float2half(uu);
        v[d * 32 + ch] = __float2half(vv);
    }
}

// ---------------------------------------------------------------------------
// K4: per-edge logits in original edge order (coalesced out writes),
//     2 edges/thread. u/v fp16 rows gathered; packed-half2 dot, fp32 combine.
// ---------------------------------------------------------------------------
__global__ void k_mlp(const int* __restrict__ src, const int* __restrict__ dst,
                      const __half2* __restrict__ u2, const __half2* __restrict__ v2,
                      const __half2* __restrict__ w2h, const float* __restrict__ b2,
                      float* __restrict__ out) {
    int t = blockIdx.x * blockDim.x + threadIdx.x;
    if (t >= MLP_T) return;
    __half2 wl[16];
#pragma unroll
    for (int q = 0; q < 4; q++) ((float4*)wl)[q] = ((const float4*)w2h)[q];
    int s[MLP_B], d[MLP_B];
#pragma unroll
    for (int k = 0; k < MLP_B; k++) {
        s[k] = src[t + k * MLP_T];
        d[k] = dst[t + k * MLP_T];
    }
    float4 ua[MLP_B][4], va[MLP_B][4];
#pragma unroll
    for (int k = 0; k < MLP_B; k++) {
        const float4* up4 = (const float4*)(u2 + s[k] * 16);
        const float4* vp4 = (const float4*)(v2 + d[k] * 16);
#pragma unroll
        for (int q = 0; q < 4; q++) { ua[k][q] = up4[q]; va[k][q] = vp4[q]; }
    }
#pragma unroll
    for (int k = 0; k < MLP_B; k++) {
        const __half2* uh = (const __half2*)ua[k];
        const __half2* vh = (const __half2*)va[k];
        const __half2 z2 = __floats2half2_rn(0.f, 0.f);
        __half2 acc0 = z2, acc1 = z2, acc2 = z2, acc3 = z2;
#pragma unroll
        for (int q = 0; q < 16; q += 4) {
            acc0 = __hfma2(h2_relu(__hadd2(uh[q + 0], vh[q + 0])), wl[q + 0], acc0);
            acc1 = __hfma2(h2_relu(__hadd2(uh[q + 1], vh[q + 1])), wl[q + 1], acc1);
            acc2 = __hfma2(h2_relu(__hadd2(uh[q + 2], vh[q + 2])), wl[q + 2], acc2);
            acc3 = __hfma2(h2_relu(__hadd2(uh[q + 3], vh[q + 3])), wl[q + 3], acc3);
        }
        float2 f0 = __half22float2(acc0);
        float2 f1 = __half22float2(acc1);
        float2 f2 = __half22float2(acc2);
        float2 f3 = __half22float2(acc3);
        float acc = b2[0] + (f0.x + f0.y) + (f1.x + f1.y) + (f2.x + f2.y) + (f3.x + f3.y);
        out[t + k * MLP_T] = acc * INV_TEMP;
    }
}

// ---------------------------------------------------------------------------
extern "C" void kernel_launch(void* const* d_in, const int* in_sizes, int n_in,
                              void* d_out, int out_size, void* d_ws, size_t ws_size,
                              hipStream_t stream) {
    const float* x       = (const float*)d_in[0];
    const int*   eidx    = (const int*)d_in[1];          // [2,E] int32
    const float* W       = (const float*)d_in[2];
    const float* att_src = (const float*)d_in[3];
    const float* att_dst = (const float*)d_in[4];
    const float* bias    = (const float*)d_in[5];
    const float* w1      = (const float*)d_in[6];
    const float* b1      = (const float*)d_in[7];
    const float* w2      = (const float*)d_in[8];
    const float* b2      = (const float*)d_in[9];
    float* out = (float*)d_out;

    const int* src = eidx;             // row 0
    const int* dst = eidx + E_EDGES;   // row 1

    // Workspace layout (~50 MB; 16B alignment holds at each boundary).
    int* gcur     = (int*)d_ws;                      // 1568 (zeroed in k_node)
    __half2* w2h  = (__half2*)(gcur + NBKT);         // 16 half2 (64 B)
    int2* recs_g  = (int2*)(w2h + 16);               // NBKT*REG_B recs (22.5 MB)
    float* a_src  = (float*)(recs_g + (size_t)NBKT * REG_B);  // 2N
    float* a_dst  = a_src + 2 * N_NODES;             // 2N
    __half2* xp2  = (__half2*)(a_dst + 2 * N_NODES); // 32N half2 (12.8 MB)
    __half* u     = (__half*)(xp2 + 32 * (size_t)N_NODES);  // 32N halves (6.4 MB)
    __half* v     = u + 32 * (size_t)N_NODES;               // 32N halves (6.4 MB)

    constexpr int BS = 256;

    // K1: node transform (+ gcur zero + w2 pack, fused)
    k_node<<<(N_NODES + BS - 1) / BS, BS, 0, stream>>>(x, W, att_src, att_dst,
                                                      xp2, a_src, a_dst, gcur, w2, w2h);

    // K2: per-(partition,tile) two-pass LDS counting sort -> bucketed records
    k_split<<<NPART * NTH, BS, 0, stream>>>(src, dst, a_src, a_dst, gcur, recs_g);

    // K3: per-bucket streaming aggregation via native LDS fp32 atomics
    k_aggsum<<<NBKT, BS, 0, stream>>>(recs_g, gcur, a_src, a_dst, xp2,
                                      bias, w1, b1, u, v);

    // K4: per-edge logits (edge order, 2 edges/thread)
    k_mlp<<<(MLP_T + BS - 1) / BS, BS, 0, stream>>>(src, dst, (const __half2*)u,
                                                   (const __half2*)v, w2h, b2, out);
}

// Round 14
// 258.056 us; speedup vs baseline: 3.2282x; 3.2253x over previous
//
#include <hip/hip_runtime.h>
#include <hip/hip_fp16.h>
#include <cstdint>

// Problem constants (match reference)
constexpr int N_NODES = 100000;
constexpr int E_EDGES = 1600000;
constexpr float NEG_SLOPE = 0.2f;
constexpr float INV_TEMP = 1.0f / 0.7f;

// Partition/bucket geometry
constexpr int NPART = 8;
constexpr int PART_N = N_NODES / NPART;          // 12500
constexpr int BKT_NODES = 64;                    // nodes per bucket
constexpr int NBKT_PART = (PART_N + BKT_NODES - 1) / BKT_NODES;  // 196
constexpr int NBKT = NPART * NBKT_PART;          // 1568
constexpr int REG_B = 1792;                      // recs per bucket (mean 1024, +17 sigma)
constexpr int NR = REG_B / 256;                  // 7 recs held per thread
constexpr int THALF = 8192;                      // edges per k_split tile
constexpr int NTH = (E_EDGES + THALF - 1) / THALF;  // 196
constexpr int CAPK = 1344;                       // kept per (part,tile): mean 1024, +10.6 sigma

constexpr int MLP_B = 2;
constexpr int MLP_T = E_EDGES / MLP_B;           // 800000

__device__ __forceinline__ __half2 bits_to_h2(int bits) {
    return *reinterpret_cast<__half2*>(&bits);
}

// packed relu (no __hmax2 in ROCm 7.2 headers; __hgt2 gives packed 1/0 mask)
__device__ __forceinline__ __half2 h2_relu(__half2 a) {
    const __half2 z = __floats2half2_rn(0.f, 0.f);
    return __hmul2(a, __hgt2(a, z));
}

// ---------------------------------------------------------------------------
// K1: per-node transform. xp2[n][c] = half2(head0_c, head1_c); a_src/a_dst
//     dots [N,2] fp32. Fused: zero gcur[1568], pack w2 -> w2h[16].
// ---------------------------------------------------------------------------
__global__ void k_node(const float* __restrict__ x, const float* __restrict__ W,
                       const float* __restrict__ att_src, const float* __restrict__ att_dst,
                       __half2* __restrict__ xp2, float* __restrict__ a_src,
                       float* __restrict__ a_dst, int* __restrict__ gcur,
                       const float* __restrict__ w2, __half2* __restrict__ w2h) {
    int n = blockIdx.x * blockDim.x + threadIdx.x;
    if (blockIdx.x == 0 && threadIdx.x < 16)
        w2h[threadIdx.x] = __floats2half2_rn(w2[2 * threadIdx.x], w2[2 * threadIdx.x + 1]);
    if (n < NBKT) gcur[n] = 0;
    if (n >= N_NODES) return;
    float xi[16];
    const float4* xv = (const float4*)(x + (size_t)n * 16);
    ((float4*)xi)[0] = xv[0];
    ((float4*)xi)[1] = xv[1];
    ((float4*)xi)[2] = xv[2];
    ((float4*)xi)[3] = xv[3];
    float as0 = 0.f, as1 = 0.f, ad0 = 0.f, ad1 = 0.f;
    __half2 hbuf[32];
#pragma unroll
    for (int c = 0; c < 32; c++) {
        float acc0 = 0.f, acc1 = 0.f;
#pragma unroll
        for (int k = 0; k < 16; k++) {
            acc0 += xi[k] * W[k * 64 + c];
            acc1 += xi[k] * W[k * 64 + 32 + c];
        }
        hbuf[c] = __floats2half2_rn(acc0, acc1);
        as0 += acc0 * att_src[c];
        as1 += acc1 * att_src[32 + c];
        ad0 += acc0 * att_dst[c];
        ad1 += acc1 * att_dst[32 + c];
    }
    float4* dst4 = (float4*)(xp2 + (size_t)n * 32);
#pragma unroll
    for (int q = 0; q < 8; q++) dst4[q] = ((float4*)hbuf)[q];
    ((float2*)a_src)[n] = make_float2(as0, as1);
    ((float2*)a_dst)[n] = make_float2(ad0, ad1);
}

// ---------------------------------------------------------------------------
// K2 (k_split): one block per (partition, 8192-edge tile). Two-pass LDS
//     counting sort; all global record writes are coalesced segments.
//     Record: {s | dloc<<17, half2(w0,w1)}  (s<2^17, dloc<2^14)
// ---------------------------------------------------------------------------
__global__ void __launch_bounds__(256) k_split(
        const int* __restrict__ src, const int* __restrict__ dst,
        const float* __restrict__ a_src, const float* __restrict__ a_dst,
        int* __restrict__ gcur, int2* __restrict__ recs_g) {
    __shared__ int2 lrec[CAPK];        // 10.8 KB
    __shared__ int hist[256];          // 196 used, padded for scan
    __shared__ int sc[256];
    __shared__ int cnt2[NBKT_PART];
    __shared__ int gbase[NBKT_PART];

    int part = blockIdx.x & 7;
    int th = blockIdx.x >> 3;          // 0..195
    int tid = threadIdx.x;
    int lo = part * PART_N, hi = lo + PART_N;
    int ebase = th * THALF;

    hist[tid] = 0;
    if (tid < NBKT_PART) cnt2[tid] = 0;
    __syncthreads();

    // pass A: histogram (dst row only)
#pragma unroll
    for (int it = 0; it < THALF / (256 * 4); it++) {
        int e4 = ebase + (it * 256 + tid) * 4;
        if (e4 + 3 < E_EDGES) {
            int4 d4 = *(const int4*)(dst + e4);
            if (d4.x >= lo && d4.x < hi) atomicAdd(&hist[(d4.x - lo) >> 6], 1);
            if (d4.y >= lo && d4.y < hi) atomicAdd(&hist[(d4.y - lo) >> 6], 1);
            if (d4.z >= lo && d4.z < hi) atomicAdd(&hist[(d4.z - lo) >> 6], 1);
            if (d4.w >= lo && d4.w < hi) atomicAdd(&hist[(d4.w - lo) >> 6], 1);
        } else if (e4 < E_EDGES) {
            int nv = E_EDGES - e4;
            for (int k = 0; k < nv; k++) {
                int d = dst[e4 + k];
                if (d >= lo && d < hi) atomicAdd(&hist[(d - lo) >> 6], 1);
            }
        }
    }
    __syncthreads();

    // inclusive scan hist -> sc (256-wide)
    sc[tid] = hist[tid];
    __syncthreads();
    for (int off = 1; off < 256; off <<= 1) {
        int v = (tid >= off) ? sc[tid - off] : 0;
        __syncthreads();
        sc[tid] += v;
        __syncthreads();
    }

    // reserve global space (one atomic per bucket per block)
    if (tid < NBKT_PART)
        gbase[tid] = atomicAdd(&gcur[part * NBKT_PART + tid], hist[tid]);
    __syncthreads();

    // pass B: compute weights, write to bucket-grouped LDS slots
#pragma unroll
    for (int it = 0; it < THALF / (256 * 4); it++) {
        int e4 = ebase + (it * 256 + tid) * 4;
        int dd[4], ss[4], nv = 0;
        if (e4 + 3 < E_EDGES) {
            int4 d4 = *(const int4*)(dst + e4);
            int4 s4 = *(const int4*)(src + e4);
            dd[0] = d4.x; dd[1] = d4.y; dd[2] = d4.z; dd[3] = d4.w;
            ss[0] = s4.x; ss[1] = s4.y; ss[2] = s4.z; ss[3] = s4.w;
            nv = 4;
        } else if (e4 < E_EDGES) {
            nv = E_EDGES - e4;
            for (int k = 0; k < nv; k++) { dd[k] = dst[e4 + k]; ss[k] = src[e4 + k]; }
        }
        for (int k = 0; k < nv; k++) {
            int d = dd[k];
            if (d >= lo && d < hi) {
                int s = ss[k];
                float2 As = ((const float2*)a_src)[s];
                float2 Ad = ((const float2*)a_dst)[d];
                float e0 = As.x + Ad.x; e0 = (e0 > 0.f) ? e0 : NEG_SLOPE * e0;
                float e1 = As.y + Ad.y; e1 = (e1 > 0.f) ? e1 : NEG_SLOPE * e1;
                __half2 hw = __floats2half2_rn(__expf(e0), __expf(e1));
                int wb = *reinterpret_cast<int*>(&hw);
                int dloc = d - lo;
                int b = dloc >> 6;
                int posl = ((b > 0) ? sc[b - 1] : 0) + atomicAdd(&cnt2[b], 1);
                if (posl < CAPK) lrec[posl] = make_int2(s | (dloc << 17), wb);
            }
        }
    }
    __syncthreads();

    // pass C: coalesced segment write-out
    int kc = sc[NBKT_PART - 1]; if (kc > CAPK) kc = CAPK;
    for (int i = tid; i < kc; i += 256) {
        int2 rc = lrec[i];
        int b = rc.x >> 23;                       // dloc>>6
        int excl = (b > 0) ? sc[b - 1] : 0;
        int gpos = gbase[b] + (i - excl);
        if (gpos < REG_B)
            recs_g[(size_t)(part * NBKT_PART + b) * REG_B + gpos] = rc;
    }
}

// ---------------------------------------------------------------------------
// K3 (k_aggsort): one block per 64-node bucket. Records loaded into
//     REGISTERS (7/thread), histogrammed, then scattered ONCE into sorted
//     LDS positions (no lidx indirection, no unsorted buffer: 14.6 KB LDS).
//     Aggregation: each half-wave processes a PAIR of nodes concurrently
//     (16 gathers in flight, 2 independent chains), packed-half2 math with
//     fp16 block accumulation + fp32 flush (registers — NO LDS atomics:
//     R12/R13 showed the DS atomic pipe serializes at ~250 cyc/record).
//     Epilogue per node: self-loop + softmax mean + fused u/v factorization.
// ---------------------------------------------------------------------------
__global__ void __launch_bounds__(256) k_aggsort(
        const int2* __restrict__ recs_g, const int* __restrict__ gcur,
        const float* __restrict__ a_src, const float* __restrict__ a_dst,
        const __half2* __restrict__ xp2, const float* __restrict__ bias,
        const float* __restrict__ w1, const float* __restrict__ b1,
        __half* __restrict__ u, __half* __restrict__ v) {
    __shared__ int2 lrec2[REG_B];        // 14.3 KB (sorted records)
    __shared__ int hist[BKT_NODES];
    __shared__ int incl[BKT_NODES];      // inclusive scan
    __shared__ int cnt2[BKT_NODES];

    int gb = blockIdx.x;
    int part = gb / NBKT_PART;
    int lb = gb - part * NBKT_PART;
    int node0 = part * PART_N + lb * BKT_NODES;
    int nnodes = PART_N - lb * BKT_NODES;
    if (nnodes > BKT_NODES) nnodes = BKT_NODES;
    int tid = threadIdx.x;
    int cnt = gcur[gb]; if (cnt > REG_B) cnt = REG_B;
    const int2* breg = recs_g + (size_t)gb * REG_B;

    if (tid < BKT_NODES) { hist[tid] = 0; cnt2[tid] = 0; }
    __syncthreads();

    // load records into registers (coalesced) + histogram by node
    int2 r[NR];
#pragma unroll
    for (int j = 0; j < NR; j++) {
        int i = tid + j * 256;
        if (i < cnt) {
            r[j] = breg[i];
            atomicAdd(&hist[(r[j].x >> 17) & 63], 1);
        }
    }
    __syncthreads();

    // inclusive scan over 64 node counts
    if (tid < BKT_NODES) incl[tid] = hist[tid];
    __syncthreads();
    for (int off = 1; off < BKT_NODES; off <<= 1) {
        int vv = (tid < BKT_NODES && tid >= off) ? incl[tid - off] : 0;
        __syncthreads();
        if (tid < BKT_NODES) incl[tid] += vv;
        __syncthreads();
    }

    // scatter registers into sorted LDS positions
#pragma unroll
    for (int j = 0; j < NR; j++) {
        int i = tid + j * 256;
        if (i < cnt) {
            int n6 = (r[j].x >> 17) & 63;
            int pos = incl[n6] - hist[n6] + atomicAdd(&cnt2[n6], 1);
            lrec2[pos] = r[j];
        }
    }
    __syncthreads();

    int hwl = tid >> 5, ch = tid & 31;
    const __half2 z2 = __floats2half2_rn(0.f, 0.f);

    // 4 pairs per half-wave: nodes (hwl+16p, hwl+16p+8)
#pragma unroll
    for (int pi = 0; pi < 4; pi++) {
        int nlA = hwl + pi * 16;
        int nlB = nlA + 8;
        bool vA = nlA < nnodes, vB = nlB < nnodes;
        int cnA = vA ? hist[nlA] : 0;
        int cnB = vB ? hist[nlB] : 0;
        int stA = (cnA > 0) ? (incl[nlA] - cnA) : 0;
        int stB = (cnB > 0) ? (incl[nlB] - cnB) : 0;
        int lastA = (cnA > 0) ? cnA - 1 : 0;
        int lastB = (cnB > 0) ? cnB - 1 : 0;

        float nA0 = 0.f, nA1 = 0.f, dA0 = 0.f, dA1 = 0.f;
        float nB0 = 0.f, nB1 = 0.f, dB0 = 0.f, dB1 = 0.f;

        int maxcn = cnA > cnB ? cnA : cnB;
        for (int j = 0; j < maxcn; j += 8) {
            int2 ra[8], rb[8];
#pragma unroll
            for (int k = 0; k < 8; k++) {
                int ia = j + k; ia = (ia < cnA) ? ia : lastA;
                int ib = j + k; ib = (ib < cnB) ? ib : lastB;
                ra[k] = lrec2[stA + ia];
                rb[k] = lrec2[stB + ib];
            }
            __half2 xa[8], xb[8];
#pragma unroll
            for (int k = 0; k < 8; k++) {
                xa[k] = xp2[(ra[k].x & 0x1FFFF) * 32 + ch];
                xb[k] = xp2[(rb[k].x & 0x1FFFF) * 32 + ch];
            }
            __half2 nbA = z2, dbA = z2, nbB = z2, dbB = z2;
#pragma unroll
            for (int k = 0; k < 8; k++) {
                int wba = (j + k < cnA) ? ra[k].y : 0;   // mask tail dups
                int wbb = (j + k < cnB) ? rb[k].y : 0;
                __half2 wa = bits_to_h2(wba);
                __half2 wb = bits_to_h2(wbb);
                dbA = __hadd2(dbA, wa);
                nbA = __hfma2(wa, xa[k], nbA);
                dbB = __hadd2(dbB, wb);
                nbB = __hfma2(wb, xb[k], nbB);
            }
            float2 f;
            f = __half22float2(nbA); nA0 += f.x; nA1 += f.y;
            f = __half22float2(dbA); dA0 += f.x; dA1 += f.y;
            f = __half22float2(nbB); nB0 += f.x; nB1 += f.y;
            f = __half22float2(dbB); dB0 += f.x; dB1 += f.y;
        }

        // epilogue node A
        if (vA) {
            int d = node0 + nlA;
            float2 Ad  = ((const float2*)a_dst)[d];
            float2 As0 = ((const float2*)a_src)[d];
            float e0 = As0.x + Ad.x; e0 = (e0 > 0.f) ? e0 : NEG_SLOPE * e0;
            float e1 = As0.y + Ad.y; e1 = (e1 > 0.f) ? e1 : NEG_SLOPE * e1;
            float w00 = __expf(e0), w01 = __expf(e1);
            float2 xs = __half22float2(xp2[d * 32 + ch]);
            float num0 = nA0 + w00 * xs.x, num1 = nA1 + w01 * xs.y;
            float den0 = dA0 + w00, den1 = dA1 + w01;
            float h = 0.5f * (num0 / (den0 + 1e-16f) + num1 / (den1 + 1e-16f)) + bias[ch];
            float uu = b1[ch], vv = 0.f;
#pragma unroll
            for (int c = 0; c < 32; c++) {
                float hc = __shfl(h, c, 32);
                uu += hc * w1[c * 32 + ch];
                vv += hc * w1[(32 + c) * 32 + ch];
            }
            u[d * 32 + ch] = __float2half(uu);
            v[d * 32 + ch] = __float2half(vv);
        }
        // epilogue node B
        if (vB) {
            int d = node0 + nlB;
            float2 Ad  = ((const float2*)a_dst)[d];
            float2 As0 = ((const float2*)a_src)[d];
            float e0 = As0.x + Ad.x; e0 = (e0 > 0.f) ? e0 : NEG_SLOPE * e0;
            float e1 = As0.y + Ad.y; e1 = (e1 > 0.f) ? e1 : NEG_SLOPE * e1;
            float w00 = __expf(e0), w01 = __expf(e1);
            float2 xs = __half22float2(xp2[d * 32 + ch]);
            float num0 = nB0 + w00 * xs.x, num1 = nB1 + w01 * xs.y;
            float den0 = dB0 + w00, den1 = dB1 + w01;
            float h = 0.5f * (num0 / (den0 + 1e-16f) + num1 / (den1 + 1e-16f)) + bias[ch];
            float uu = b1[ch], vv = 0.f;
#pragma unroll
            for (int c = 0; c < 32; c++) {
                float hc = __shfl(h, c, 32);
                uu += hc * w1[c * 32 + ch];
                vv += hc * w1[(32 + c) * 32 + ch];
            }
            u[d * 32 + ch] = __float2half(uu);
            v[d * 32 + ch] = __float2half(vv);
        }
    }
}

// ---------------------------------------------------------------------------
// K4: per-edge logits in original edge order (coalesced out writes),
//     2 edges/thread. u/v fp16 rows gathered; packed-half2 dot, fp32 combine.
// ---------------------------------------------------------------------------
__global__ void k_mlp(const int* __restrict__ src, const int* __restrict__ dst,
                      const __half2* __restrict__ u2, const __half2* __restrict__ v2,
                      const __half2* __restrict__ w2h, const float* __restrict__ b2,
                      float* __restrict__ out) {
    int t = blockIdx.x * blockDim.x + threadIdx.x;
    if (t >= MLP_T) return;
    __half2 wl[16];
#pragma unroll
    for (int q = 0; q < 4; q++) ((float4*)wl)[q] = ((const float4*)w2h)[q];
    int s[MLP_B], d[MLP_B];
#pragma unroll
    for (int k = 0; k < MLP_B; k++) {
        s[k] = src[t + k * MLP_T];
        d[k] = dst[t + k * MLP_T];
    }
    float4 ua[MLP_B][4], va[MLP_B][4];
#pragma unroll
    for (int k = 0; k < MLP_B; k++) {
        const float4* up4 = (const float4*)(u2 + s[k] * 16);
        const float4* vp4 = (const float4*)(v2 + d[k] * 16);
#pragma unroll
        for (int q = 0; q < 4; q++) { ua[k][q] = up4[q]; va[k][q] = vp4[q]; }
    }
#pragma unroll
    for (int k = 0; k < MLP_B; k++) {
        const __half2* uh = (const __half2*)ua[k];
        const __half2* vh = (const __half2*)va[k];
        const __half2 z2 = __floats2half2_rn(0.f, 0.f);
        __half2 acc0 = z2, acc1 = z2, acc2 = z2, acc3 = z2;
#pragma unroll
        for (int q = 0; q < 16; q += 4) {
            acc0 = __hfma2(h2_relu(__hadd2(uh[q + 0], vh[q + 0])), wl[q + 0], acc0);
            acc1 = __hfma2(h2_relu(__hadd2(uh[q + 1], vh[q + 1])), wl[q + 1], acc1);
            acc2 = __hfma2(h2_relu(__hadd2(uh[q + 2], vh[q + 2])), wl[q + 2], acc2);
            acc3 = __hfma2(h2_relu(__hadd2(uh[q + 3], vh[q + 3])), wl[q + 3], acc3);
        }
        float2 f0 = __half22float2(acc0);
        float2 f1 = __half22float2(acc1);
        float2 f2 = __half22float2(acc2);
        float2 f3 = __half22float2(acc3);
        float acc = b2[0] + (f0.x + f0.y) + (f1.x + f1.y) + (f2.x + f2.y) + (f3.x + f3.y);
        out[t + k * MLP_T] = acc * INV_TEMP;
    }
}

// ---------------------------------------------------------------------------
extern "C" void kernel_launch(void* const* d_in, const int* in_sizes, int n_in,
                              void* d_out, int out_size, void* d_ws, size_t ws_size,
                              hipStream_t stream) {
    const float* x       = (const float*)d_in[0];
    const int*   eidx    = (const int*)d_in[1];          // [2,E] int32
    const float* W       = (const float*)d_in[2];
    const float* att_src = (const float*)d_in[3];
    const float* att_dst = (const float*)d_in[4];
    const float* bias    = (const float*)d_in[5];
    const float* w1      = (const float*)d_in[6];
    const float* b1      = (const float*)d_in[7];
    const float* w2      = (const float*)d_in[8];
    const float* b2      = (const float*)d_in[9];
    float* out = (float*)d_out;

    const int* src = eidx;             // row 0
    const int* dst = eidx + E_EDGES;   // row 1

    // Workspace layout (~50 MB; 16B alignment holds at each boundary).
    int* gcur     = (int*)d_ws;                      // 1568 (zeroed in k_node)
    __half2* w2h  = (__half2*)(gcur + NBKT);         // 16 half2 (64 B)
    int2* recs_g  = (int2*)(w2h + 16);               // NBKT*REG_B recs (22.5 MB)
    float* a_src  = (float*)(recs_g + (size_t)NBKT * REG_B);  // 2N
    float* a_dst  = a_src + 2 * N_NODES;             // 2N
    __half2* xp2  = (__half2*)(a_dst + 2 * N_NODES); // 32N half2 (12.8 MB)
    __half* u     = (__half*)(xp2 + 32 * (size_t)N_NODES);  // 32N halves (6.4 MB)
    __half* v     = u + 32 * (size_t)N_NODES;               // 32N halves (6.4 MB)

    constexpr int BS = 256;

    // K1: node transform (+ gcur zero + w2 pack, fused)
    k_node<<<(N_NODES + BS - 1) / BS, BS, 0, stream>>>(x, W, att_src, att_dst,
                                                      xp2, a_src, a_dst, gcur, w2, w2h);

    // K2: per-(partition,tile) two-pass LDS counting sort -> bucketed records
    k_split<<<NPART * NTH, BS, 0, stream>>>(src, dst, a_src, a_dst, gcur, recs_g);

    // K3: per-bucket register-sort + paired-node aggregation (no LDS atomics)
    k_aggsort<<<NBKT, BS, 0, stream>>>(recs_g, gcur, a_src, a_dst, xp2,
                                       bias, w1, b1, u, v);

    // K4: per-edge logits (edge order, 2 edges/thread)
    k_mlp<<<(MLP_T + BS - 1) / BS, BS, 0, stream>>>(src, dst, (const __half2*)u,
                                                   (const __half2*)v, w2h, b2, out);
}